// Round 1
// baseline (1623.345 us; speedup 1.0000x reference)
//
#include <hip/hip_runtime.h>
#include <hip/hip_bf16.h>

#define N_ENT   8192
#define N_USR   16384
#define CH      64
#define N_EDGEC 1000000
#define NNZC    500000
#define TOPKC   10
#define NRELM1  8

static __device__ __forceinline__ float waveReduceSum(float v){
#pragma unroll
  for(int o=1;o<64;o<<=1) v += __shfl_xor(v,o,64);
  return v;
}
static __device__ __forceinline__ float waveReduceMax(float v){
#pragma unroll
  for(int o=1;o<64;o<<=1) v = fmaxf(v, __shfl_xor(v,o,64));
  return v;
}

// ---------------- sorting (counting sort by segment key) ----------------
__global__ void k_hist(const int* __restrict__ keys, int n, int* __restrict__ hist){
  int i = blockIdx.x*blockDim.x + threadIdx.x;
  int stride = gridDim.x*blockDim.x;
  for(; i<n; i+=stride) atomicAdd(&hist[keys[i]], 1);
}

__global__ __launch_bounds__(1024) void k_scan(const int* __restrict__ hist,
                                               int* __restrict__ start,
                                               int* __restrict__ cursor, int n){
  __shared__ int part[1024];
  int t = threadIdx.x;
  int chunk = n/1024;
  int base = t*chunk;
  int s = 0;
  for(int i=0;i<chunk;i++) s += hist[base+i];
  part[t] = s; __syncthreads();
  for(int off=1; off<1024; off<<=1){
    int v = (t>=off) ? part[t-off] : 0;
    __syncthreads();
    part[t] += v;
    __syncthreads();
  }
  int run = (t==0) ? 0 : part[t-1];
  for(int i=0;i<chunk;i++){
    start[base+i] = run; cursor[base+i] = run;
    run += hist[base+i];
  }
  if(t==1023) start[n] = run;
}

__global__ void k_scatter_sort(const int* __restrict__ keys, int n,
                               int* __restrict__ cursor, int* __restrict__ sorted){
  int i = blockIdx.x*blockDim.x + threadIdx.x;
  int stride = gridDim.x*blockDim.x;
  for(; i<n; i+=stride){
    int pos = atomicAdd(&cursor[keys[i]], 1);
    sorted[pos] = i;
  }
}

// ---------------- row normalize (cn and l2norm) ----------------
__global__ __launch_bounds__(256) void k_rownorm(const float* __restrict__ in,
                                                 float* __restrict__ out,
                                                 int rows, float eps){
  int wave = threadIdx.x>>6, lane = threadIdx.x&63;
  int r = blockIdx.x*4 + wave;
  if(r>=rows) return;
  float v = in[(size_t)r*CH+lane];
  float ss = waveReduceSum(v*v);
  float nrm = sqrtf(ss);
  out[(size_t)r*CH+lane] = v / fmaxf(nrm, eps);
}

// ---------------- sim GEMM: C = A * A^T, K=64, f32 vector ALU ----------------
// 128x128 block tile, 256 threads, 8x8 micro-tile, transposed LDS for float4 reads.
__global__ __launch_bounds__(256,2) void k_gemm_nt(const float* __restrict__ A,
                                                   float* __restrict__ C){
  __shared__ float As[CH][132];
  __shared__ float Bs[CH][132];
  const int tid = threadIdx.x;
  const int bi = blockIdx.y*128, bj = blockIdx.x*128;
#pragma unroll
  for(int k=0;k<8;k++){
    int idx = tid + k*256;          // 2048 float4 loads per tile pair
    int row = idx>>4;
    int c4  = (idx&15)*4;
    float4 va = ((const float4*)(A + (size_t)(bi+row)*CH))[c4>>2];
    As[c4+0][row]=va.x; As[c4+1][row]=va.y; As[c4+2][row]=va.z; As[c4+3][row]=va.w;
    float4 vb = ((const float4*)(A + (size_t)(bj+row)*CH))[c4>>2];
    Bs[c4+0][row]=vb.x; Bs[c4+1][row]=vb.y; Bs[c4+2][row]=vb.z; Bs[c4+3][row]=vb.w;
  }
  __syncthreads();
  const int tx = tid&15, ty = tid>>4;
  float acc[8][8];
#pragma unroll
  for(int i=0;i<8;i++)
#pragma unroll
    for(int j=0;j<8;j++) acc[i][j]=0.f;
#pragma unroll 8
  for(int k=0;k<CH;k++){
    float4 a0 = *(const float4*)&As[k][ty*8];
    float4 a1 = *(const float4*)&As[k][ty*8+4];
    float4 b0 = *(const float4*)&Bs[k][tx*8];
    float4 b1 = *(const float4*)&Bs[k][tx*8+4];
    float a[8]={a0.x,a0.y,a0.z,a0.w,a1.x,a1.y,a1.z,a1.w};
    float b[8]={b0.x,b0.y,b0.z,b0.w,b1.x,b1.y,b1.z,b1.w};
#pragma unroll
    for(int i=0;i<8;i++)
#pragma unroll
      for(int j=0;j<8;j++) acc[i][j] = fmaf(a[i], b[j], acc[i][j]);
  }
#pragma unroll
  for(int i=0;i<8;i++){
    float4 o0 = {acc[i][0],acc[i][1],acc[i][2],acc[i][3]};
    float4 o1 = {acc[i][4],acc[i][5],acc[i][6],acc[i][7]};
    float* crow = C + (size_t)(bi+ty*8+i)*N_ENT + bj + tx*8;
    *(float4*)crow = o0;
    *((float4*)crow+1) = o1;
  }
}

// ---------------- per-row top-k via monotonic u64 keys ----------------
// key = mapped_float<<32 | (0xFFFFFFFF - col): larger value wins; ties -> smaller col.
__global__ __launch_bounds__(256) void k_topk(const float* __restrict__ S,
                                              int* __restrict__ knn_idx,
                                              float* __restrict__ knn_val,
                                              float* __restrict__ rowsum){
  const int row = blockIdx.x;
  const float* srow = S + (size_t)row*N_ENT;
  const int t = threadIdx.x;
  unsigned long long loc[TOPKC];
#pragma unroll
  for(int i=0;i<TOPKC;i++) loc[i]=0ull;
  for(int c=t;c<N_ENT;c+=256){
    float v = srow[c];
    unsigned u = __float_as_uint(v);
    u = (u & 0x80000000u) ? ~u : (u | 0x80000000u);
    unsigned long long key = ((unsigned long long)u<<32)
                           | (unsigned long long)(0xFFFFFFFFu - (unsigned)c);
    if(key > loc[TOPKC-1]){
      int p = TOPKC-1;
      while(p>0 && loc[p-1]<key){ loc[p]=loc[p-1]; --p; }
      loc[p]=key;
    }
  }
  __shared__ unsigned long long pool[256*TOPKC];
  __shared__ unsigned long long red[256];
#pragma unroll
  for(int i=0;i<TOPKC;i++) pool[t*TOPKC+i]=loc[i];
  float rs = 0.f;
  for(int sel=0; sel<TOPKC; sel++){
    __syncthreads();
    unsigned long long m=0ull;
#pragma unroll
    for(int i=0;i<TOPKC;i++){ unsigned long long pv=pool[t*TOPKC+i]; if(pv>m) m=pv; }
    red[t]=m; __syncthreads();
    for(int off=128; off>0; off>>=1){
      if(t<off && red[t+off]>red[t]) red[t]=red[t+off];
      __syncthreads();
    }
    unsigned long long w = red[0];
#pragma unroll
    for(int i=0;i<TOPKC;i++) if(pool[t*TOPKC+i]==w) pool[t*TOPKC+i]=0ull;
    if(t==0){
      unsigned mk = (unsigned)(w>>32);
      unsigned uo = (mk & 0x80000000u) ? (mk ^ 0x80000000u) : ~mk;
      float v = __uint_as_float(uo);
      int col = (int)(0xFFFFFFFFu - (unsigned)(w & 0xFFFFFFFFu));
      knn_idx[row*TOPKC+sel] = col;
      knn_val[row*TOPKC+sel] = v;
      rs += v;
    }
  }
  if(t==0) rowsum[row] = rs;
}

// ---------------- q[i][r] = ||ent_i * W_r||^2 ----------------
__global__ __launch_bounds__(256) void k_q(const float* __restrict__ ent,
                                           const float* __restrict__ W,
                                           float* __restrict__ q){
  int wave=threadIdx.x>>6, lane=threadIdx.x&63;
  int r = blockIdx.x*4+wave;
  if(r>=N_ENT) return;
  float x = ent[(size_t)r*CH+lane];
#pragma unroll
  for(int rel=0; rel<NRELM1; rel++){
    float tt = x*W[rel*CH+lane];
    float s = waveReduceSum(tt*tt);
    if(lane==0) q[r*NRELM1+rel]=s;
  }
}

// ---------------- per-head edge aggregation (sorted segments) ----------------
__global__ __launch_bounds__(256) void k_edge_agg(
    const int* __restrict__ tail, const int* __restrict__ etype,
    const int* __restrict__ startE, const int* __restrict__ sortedE,
    const float* __restrict__ ent, const float* __restrict__ W,
    const float* __restrict__ q, float* __restrict__ agg){
  int wave=threadIdx.x>>6, lane=threadIdx.x&63;
  int h = blockIdx.x*4+wave;
  if(h>=N_ENT) return;
  int s = startE[h], e2 = startE[h+1];
  float mx = 0.f;                     // att >= 0 always (product of squared norms)
  for(int p=s+lane; p<e2; p+=64){
    int eid = sortedE[p];
    int r = etype[eid]-1;
    float att = q[h*NRELM1+r]*q[tail[eid]*NRELM1+r];
    mx = fmaxf(mx, att);
  }
  mx = waveReduceMax(mx);
  float dn = 0.f;
  for(int p=s+lane; p<e2; p+=64){
    int eid = sortedE[p];
    int r = etype[eid]-1;
    float att = q[h*NRELM1+r]*q[tail[eid]*NRELM1+r];
    dn += expf(att-mx);
  }
  dn = waveReduceSum(dn);
  float inv = (dn>0.f) ? 1.f/dn : 0.f;
  float acc = 0.f;
  for(int p=s; p<e2; p++){
    int eid = sortedE[p];
    int tl  = tail[eid];
    int r   = etype[eid]-1;
    float att = q[h*NRELM1+r]*q[tl*NRELM1+r];
    float wgt = expf(att-mx)*inv;
    acc += wgt * ent[(size_t)tl*CH+lane] * W[r*CH+lane];
  }
  agg[(size_t)h*CH+lane] = acc;
}

// ---------------- per-user: sparse agg + gated score + l2norm + residual ----------------
__global__ __launch_bounds__(256) void k_user(
    const int* __restrict__ icols, const float* __restrict__ ivals,
    const int* __restrict__ startU, const int* __restrict__ sortedU,
    const float* __restrict__ ent, const float* __restrict__ W,
    float* __restrict__ usr, float* __restrict__ usr_res){
  int wave=threadIdx.x>>6, lane=threadIdx.x&63;
  int u = blockIdx.x*4+wave;
  if(u>=N_USR) return;
  float ue = usr[(size_t)u*CH+lane];
  float l[NRELM1];
#pragma unroll
  for(int r=0;r<NRELM1;r++) l[r] = waveReduceSum(ue*W[r*CH+lane]);
  float lm = l[0];
#pragma unroll
  for(int r=1;r<NRELM1;r++) lm = fmaxf(lm,l[r]);
  float se=0.f;
#pragma unroll
  for(int r=0;r<NRELM1;r++){ l[r]=expf(l[r]-lm); se+=l[r]; }
  float inv = 1.f/se;
  float g = 0.f;
#pragma unroll
  for(int r=0;r<NRELM1;r++) g = fmaf(l[r]*inv, W[r*CH+lane], g);
  float acc=0.f;
  int s=startU[u], e2=startU[u+1];
  for(int p=s;p<e2;p++){
    int id = sortedU[p];
    acc = fmaf(ivals[id], ent[(size_t)icols[id]*CH+lane], acc);
  }
  float res = acc*(1.f+g);
  float nrm = sqrtf(waveReduceSum(res*res));
  float outv = res / fmaxf(nrm, 1e-12f);
  usr_res[(size_t)u*CH+lane] += outv;
  usr[(size_t)u*CH+lane] = outv;
}

// ---------------- entity finalize: l2norm + residual ----------------
__global__ __launch_bounds__(256) void k_entfin(const float* __restrict__ agg,
                                                float* __restrict__ cur,
                                                float* __restrict__ res){
  int wave=threadIdx.x>>6, lane=threadIdx.x&63;
  int r = blockIdx.x*4+wave;
  if(r>=N_ENT) return;
  float v = agg[(size_t)r*CH+lane];
  float nrm = sqrtf(waveReduceSum(v*v));
  float outv = v / fmaxf(nrm, 1e-12f);
  cur[(size_t)r*CH+lane]=outv;
  res[(size_t)r*CH+lane]+=outv;
}

// ---------------- final adj scatter: adj[r,c] += coef * dinv[r]*v*dinv[c] ----------------
__global__ void k_scatter_adj(const int* __restrict__ knn_idx,
                              const float* __restrict__ knn_val,
                              const float* __restrict__ rowsum,
                              float coef, float* __restrict__ adj){
  int i = blockIdx.x*blockDim.x+threadIdx.x;
  if(i>=N_ENT*TOPKC) return;
  int row = i/TOPKC;
  int col = knn_idx[i];
  float v = knn_val[i];
  float dv = coef * v / (sqrtf(rowsum[row]) * sqrtf(rowsum[col]));
  atomicAdd(&adj[(size_t)row*N_ENT+col], dv);
}

extern "C" void kernel_launch(void* const* d_in, const int* in_sizes, int n_in,
                              void* d_out, int out_size, void* d_ws, size_t ws_size,
                              hipStream_t stream){
  const float* user_emb   = (const float*)d_in[0];
  const float* entity_emb = (const float*)d_in[1];
  const int*   edge_index = (const int*)d_in[2];
  const int*   edge_type  = (const int*)d_in[3];
  const int*   inter_idx  = (const int*)d_in[4];
  const float* inter_vals = (const float*)d_in[5];
  const float* W          = (const float*)d_in[6];

  const int* head  = edge_index;
  const int* tail  = edge_index + N_EDGEC;
  const int* irows = inter_idx;
  const int* icols = inter_idx + NNZC;

  float* out     = (float*)d_out;
  float* ent_res = out;
  float* usr_res = out + (size_t)N_ENT*CH;
  float* adj     = out + (size_t)N_ENT*CH + (size_t)N_USR*CH;

  char* wp = (char*)d_ws;
  auto alloc = [&](size_t bytes)->void*{
    void* p = (void*)wp; wp += (bytes+255)/256*256; return p;
  };
  float* cn      = (float*)alloc((size_t)N_ENT*CH*4);
  float* cur_ent = (float*)alloc((size_t)N_ENT*CH*4);
  float* cur_usr = (float*)alloc((size_t)N_USR*CH*4);
  float* agg     = (float*)alloc((size_t)N_ENT*CH*4);
  float* q       = (float*)alloc((size_t)N_ENT*NRELM1*4);
  int*   histE   = (int*)alloc((size_t)N_ENT*4);
  int*   startE  = (int*)alloc((size_t)(N_ENT+1)*4);
  int*   cursorE = (int*)alloc((size_t)N_ENT*4);
  int*   sortedE = (int*)alloc((size_t)N_EDGEC*4);
  int*   histU   = (int*)alloc((size_t)N_USR*4);
  int*   startU  = (int*)alloc((size_t)(N_USR+1)*4);
  int*   cursorU = (int*)alloc((size_t)N_USR*4);
  int*   sortedU = (int*)alloc((size_t)NNZC*4);
  int*   knn_idx0= (int*)alloc((size_t)N_ENT*TOPKC*4);
  float* knn_val0= (float*)alloc((size_t)N_ENT*TOPKC*4);
  float* rowsum0 = (float*)alloc((size_t)N_ENT*4);
  int*   knn_idx1= (int*)alloc((size_t)N_ENT*TOPKC*4);
  float* knn_val1= (float*)alloc((size_t)N_ENT*TOPKC*4);
  float* rowsum1 = (float*)alloc((size_t)N_ENT*4);

  // init
  hipMemsetAsync(histE, 0, (size_t)N_ENT*4, stream);
  hipMemsetAsync(histU, 0, (size_t)N_USR*4, stream);
  hipMemcpyAsync(ent_res, entity_emb, (size_t)N_ENT*CH*4, hipMemcpyDeviceToDevice, stream);
  hipMemcpyAsync(usr_res, user_emb,   (size_t)N_USR*CH*4, hipMemcpyDeviceToDevice, stream);
  hipMemcpyAsync(cur_ent, entity_emb, (size_t)N_ENT*CH*4, hipMemcpyDeviceToDevice, stream);
  hipMemcpyAsync(cur_usr, user_emb,   (size_t)N_USR*CH*4, hipMemcpyDeviceToDevice, stream);

  // counting sorts (edges by head, inter by row) — reused by both hops
  k_hist<<<1024,256,0,stream>>>(head, N_EDGEC, histE);
  k_hist<<<512,256,0,stream>>>(irows, NNZC, histU);
  k_scan<<<1,1024,0,stream>>>(histE, startE, cursorE, N_ENT);
  k_scan<<<1,1024,0,stream>>>(histU, startU, cursorU, N_USR);
  k_scatter_sort<<<1024,256,0,stream>>>(head, N_EDGEC, cursorE, sortedE);
  k_scatter_sort<<<512,256,0,stream>>>(irows, NNZC, cursorU, sortedU);

  dim3 gg(N_ENT/128, N_ENT/128);

  // build_adj #1 on original entity_emb (sim matrix staged in the adj output region)
  k_rownorm<<<N_ENT/4,256,0,stream>>>(entity_emb, cn, N_ENT, 0.f);
  k_gemm_nt<<<gg,256,0,stream>>>(cn, adj);
  k_topk<<<N_ENT,256,0,stream>>>(adj, knn_idx0, knn_val0, rowsum0);

  // 2 hops
  for(int hop=0; hop<2; ++hop){
    k_q<<<N_ENT/4,256,0,stream>>>(cur_ent, W, q);
    k_edge_agg<<<N_ENT/4,256,0,stream>>>(tail, edge_type, startE, sortedE,
                                         cur_ent, W, q, agg);
    k_user<<<N_USR/4,256,0,stream>>>(icols, inter_vals, startU, sortedU,
                                     cur_ent, W, cur_usr, usr_res);
    k_entfin<<<N_ENT/4,256,0,stream>>>(agg, cur_ent, ent_res);
  }

  // build_adj #2 on entity_res_emb
  k_rownorm<<<N_ENT/4,256,0,stream>>>(ent_res, cn, N_ENT, 0.f);
  k_gemm_nt<<<gg,256,0,stream>>>(cn, adj);
  k_topk<<<N_ENT,256,0,stream>>>(adj, knn_idx1, knn_val1, rowsum1);

  // item_adj = 0.5*new + 0.5*origin, materialized dense
  hipMemsetAsync(adj, 0, (size_t)N_ENT*N_ENT*4, stream);
  int nsc = (N_ENT*TOPKC+255)/256;
  k_scatter_adj<<<nsc,256,0,stream>>>(knn_idx1, knn_val1, rowsum1, 0.5f, adj);
  k_scatter_adj<<<nsc,256,0,stream>>>(knn_idx0, knn_val0, rowsum0, 0.5f, adj);
}

// Round 2
// 1375.133 us; speedup vs baseline: 1.1805x; 1.1805x over previous
//
#include <hip/hip_runtime.h>
#include <hip/hip_bf16.h>

#define N_ENT   8192
#define N_USR   16384
#define CH      64
#define N_EDGEC 1000000
#define NNZC    500000
#define TOPKC   10
#define NRELM1  8

static __device__ __forceinline__ float waveReduceSum(float v){
#pragma unroll
  for(int o=1;o<64;o<<=1) v += __shfl_xor(v,o,64);
  return v;
}
static __device__ __forceinline__ float waveReduceMax(float v){
#pragma unroll
  for(int o=1;o<64;o<<=1) v = fmaxf(v, __shfl_xor(v,o,64));
  return v;
}

// ---------------- sorting (counting sort by segment key) ----------------
__global__ void k_hist(const int* __restrict__ keys, int n, int* __restrict__ hist){
  int i = blockIdx.x*blockDim.x + threadIdx.x;
  int stride = gridDim.x*blockDim.x;
  for(; i<n; i+=stride) atomicAdd(&hist[keys[i]], 1);
}

__global__ __launch_bounds__(1024) void k_scan(const int* __restrict__ hist,
                                               int* __restrict__ start,
                                               int* __restrict__ cursor, int n){
  __shared__ int part[1024];
  int t = threadIdx.x;
  int chunk = n/1024;
  int base = t*chunk;
  int s = 0;
  for(int i=0;i<chunk;i++) s += hist[base+i];
  part[t] = s; __syncthreads();
  for(int off=1; off<1024; off<<=1){
    int v = (t>=off) ? part[t-off] : 0;
    __syncthreads();
    part[t] += v;
    __syncthreads();
  }
  int run = (t==0) ? 0 : part[t-1];
  for(int i=0;i<chunk;i++){
    start[base+i] = run; cursor[base+i] = run;
    run += hist[base+i];
  }
  if(t==1023) start[n] = run;
}

__global__ void k_scatter_sort(const int* __restrict__ keys, int n,
                               int* __restrict__ cursor, int* __restrict__ sorted){
  int i = blockIdx.x*blockDim.x + threadIdx.x;
  int stride = gridDim.x*blockDim.x;
  for(; i<n; i+=stride){
    int pos = atomicAdd(&cursor[keys[i]], 1);
    sorted[pos] = i;
  }
}

// ---------------- row normalize (cn and l2norm) ----------------
__global__ __launch_bounds__(256) void k_rownorm(const float* __restrict__ in,
                                                 float* __restrict__ out,
                                                 int rows, float eps){
  int wave = threadIdx.x>>6, lane = threadIdx.x&63;
  int r = blockIdx.x*4 + wave;
  if(r>=rows) return;
  float v = in[(size_t)r*CH+lane];
  float ss = waveReduceSum(v*v);
  float nrm = sqrtf(ss);
  out[(size_t)r*CH+lane] = v / fmaxf(nrm, eps);
}

// ---------------- sim GEMM: C = A * A^T, K=64, f32 vector ALU ----------------
__global__ __launch_bounds__(256,2) void k_gemm_nt(const float* __restrict__ A,
                                                   float* __restrict__ C){
  __shared__ float As[CH][132];
  __shared__ float Bs[CH][132];
  const int tid = threadIdx.x;
  const int bi = blockIdx.y*128, bj = blockIdx.x*128;
#pragma unroll
  for(int k=0;k<8;k++){
    int idx = tid + k*256;
    int row = idx>>4;
    int c4  = (idx&15)*4;
    float4 va = ((const float4*)(A + (size_t)(bi+row)*CH))[c4>>2];
    As[c4+0][row]=va.x; As[c4+1][row]=va.y; As[c4+2][row]=va.z; As[c4+3][row]=va.w;
    float4 vb = ((const float4*)(A + (size_t)(bj+row)*CH))[c4>>2];
    Bs[c4+0][row]=vb.x; Bs[c4+1][row]=vb.y; Bs[c4+2][row]=vb.z; Bs[c4+3][row]=vb.w;
  }
  __syncthreads();
  const int tx = tid&15, ty = tid>>4;
  float acc[8][8];
#pragma unroll
  for(int i=0;i<8;i++)
#pragma unroll
    for(int j=0;j<8;j++) acc[i][j]=0.f;
#pragma unroll 8
  for(int k=0;k<CH;k++){
    float4 a0 = *(const float4*)&As[k][ty*8];
    float4 a1 = *(const float4*)&As[k][ty*8+4];
    float4 b0 = *(const float4*)&Bs[k][tx*8];
    float4 b1 = *(const float4*)&Bs[k][tx*8+4];
    float a[8]={a0.x,a0.y,a0.z,a0.w,a1.x,a1.y,a1.z,a1.w};
    float b[8]={b0.x,b0.y,b0.z,b0.w,b1.x,b1.y,b1.z,b1.w};
#pragma unroll
    for(int i=0;i<8;i++)
#pragma unroll
      for(int j=0;j<8;j++) acc[i][j] = fmaf(a[i], b[j], acc[i][j]);
  }
#pragma unroll
  for(int i=0;i<8;i++){
    float4 o0 = {acc[i][0],acc[i][1],acc[i][2],acc[i][3]};
    float4 o1 = {acc[i][4],acc[i][5],acc[i][6],acc[i][7]};
    float* crow = C + (size_t)(bi+ty*8+i)*N_ENT + bj + tx*8;
    *(float4*)crow = o0;
    *((float4*)crow+1) = o1;
  }
}

// ---------------- per-row top-k: one wave per row, register-only ----------------
// key = mapped_float<<32 | (0xFFFFFFFF - col): larger value wins; ties -> smaller col.
__global__ __launch_bounds__(256) void k_topk(const float* __restrict__ S,
                                              int* __restrict__ knn_idx,
                                              float* __restrict__ knn_val,
                                              float* __restrict__ rowsum){
  const int wave = threadIdx.x>>6, lane = threadIdx.x&63;
  const int row = blockIdx.x*4 + wave;
  if(row>=N_ENT) return;
  const float4* s4 = (const float4*)(S + (size_t)row*N_ENT);

  unsigned long long loc[TOPKC];
#pragma unroll
  for(int i=0;i<TOPKC;i++) loc[i]=0ull;

#pragma unroll 4
  for(int it=0; it<N_ENT/(64*4); ++it){
    int vi = it*64 + lane;          // float4 index; wave reads contiguous 1KiB
    float4 v = s4[vi];
    int c0 = vi*4;
    float vv[4] = {v.x, v.y, v.z, v.w};
#pragma unroll
    for(int j=0;j<4;j++){
      unsigned u = __float_as_uint(vv[j]);
      u = (u & 0x80000000u) ? ~u : (u | 0x80000000u);
      unsigned long long key = ((unsigned long long)u<<32)
                             | (unsigned long long)(0xFFFFFFFFu - (unsigned)(c0+j));
      if(key > loc[TOPKC-1]){
        unsigned long long t = key;
#pragma unroll
        for(int z=0; z<TOPKC; ++z){
          if(t > loc[z]){ unsigned long long tmp=loc[z]; loc[z]=t; t=tmp; }
        }
      }
    }
  }

  // wave merge: 10 rounds of shfl-max; winner lane pops its head. No LDS, no barriers.
  float rs = 0.f;
  for(int sel=0; sel<TOPKC; ++sel){
    unsigned long long m = loc[0];
#pragma unroll
    for(int o=1;o<64;o<<=1){
      unsigned long long other = __shfl_xor(m, o, 64);
      if(other > m) m = other;
    }
    if(loc[0] == m){
#pragma unroll
      for(int z=0;z<TOPKC-1;++z) loc[z]=loc[z+1];
      loc[TOPKC-1]=0ull;
    }
    if(lane==0){
      unsigned mk = (unsigned)(m>>32);
      unsigned uo = (mk & 0x80000000u) ? (mk ^ 0x80000000u) : ~mk;
      float v = __uint_as_float(uo);
      int col = (int)(0xFFFFFFFFu - (unsigned)(m & 0xFFFFFFFFu));
      knn_idx[row*TOPKC+sel] = col;
      knn_val[row*TOPKC+sel] = v;
      rs += v;
    }
  }
  if(lane==0) rowsum[row] = rs;
}

// ---------------- q[i][r] = ||ent_i * W_r||^2 ----------------
__global__ __launch_bounds__(256) void k_q(const float* __restrict__ ent,
                                           const float* __restrict__ W,
                                           float* __restrict__ q){
  int wave=threadIdx.x>>6, lane=threadIdx.x&63;
  int r = blockIdx.x*4+wave;
  if(r>=N_ENT) return;
  float x = ent[(size_t)r*CH+lane];
#pragma unroll
  for(int rel=0; rel<NRELM1; rel++){
    float tt = x*W[rel*CH+lane];
    float s = waveReduceSum(tt*tt);
    if(lane==0) q[r*NRELM1+rel]=s;
  }
}

// ---------------- per-head edge aggregation (sorted segments) ----------------
__global__ __launch_bounds__(256) void k_edge_agg(
    const int* __restrict__ tail, const int* __restrict__ etype,
    const int* __restrict__ startE, const int* __restrict__ sortedE,
    const float* __restrict__ ent, const float* __restrict__ W,
    const float* __restrict__ q, float* __restrict__ agg){
  int wave=threadIdx.x>>6, lane=threadIdx.x&63;
  int h = blockIdx.x*4+wave;
  if(h>=N_ENT) return;
  int s = startE[h], e2 = startE[h+1];
  float mx = 0.f;                     // att >= 0 always
  for(int p=s+lane; p<e2; p+=64){
    int eid = sortedE[p];
    int r = etype[eid]-1;
    float att = q[h*NRELM1+r]*q[tail[eid]*NRELM1+r];
    mx = fmaxf(mx, att);
  }
  mx = waveReduceMax(mx);
  float dn = 0.f;
  for(int p=s+lane; p<e2; p+=64){
    int eid = sortedE[p];
    int r = etype[eid]-1;
    float att = q[h*NRELM1+r]*q[tail[eid]*NRELM1+r];
    dn += expf(att-mx);
  }
  dn = waveReduceSum(dn);
  float inv = (dn>0.f) ? 1.f/dn : 0.f;
  float acc = 0.f;
  for(int p=s; p<e2; p++){
    int eid = sortedE[p];
    int tl  = tail[eid];
    int r   = etype[eid]-1;
    float att = q[h*NRELM1+r]*q[tl*NRELM1+r];
    float wgt = expf(att-mx)*inv;
    acc += wgt * ent[(size_t)tl*CH+lane] * W[r*CH+lane];
  }
  agg[(size_t)h*CH+lane] = acc;
}

// ---------------- per-user: sparse agg + gated score + l2norm + residual ----------------
__global__ __launch_bounds__(256) void k_user(
    const int* __restrict__ icols, const float* __restrict__ ivals,
    const int* __restrict__ startU, const int* __restrict__ sortedU,
    const float* __restrict__ ent, const float* __restrict__ W,
    float* __restrict__ usr, float* __restrict__ usr_res){
  int wave=threadIdx.x>>6, lane=threadIdx.x&63;
  int u = blockIdx.x*4+wave;
  if(u>=N_USR) return;
  float ue = usr[(size_t)u*CH+lane];
  float l[NRELM1];
#pragma unroll
  for(int r=0;r<NRELM1;r++) l[r] = waveReduceSum(ue*W[r*CH+lane]);
  float lm = l[0];
#pragma unroll
  for(int r=1;r<NRELM1;r++) lm = fmaxf(lm,l[r]);
  float se=0.f;
#pragma unroll
  for(int r=0;r<NRELM1;r++){ l[r]=expf(l[r]-lm); se+=l[r]; }
  float inv = 1.f/se;
  float g = 0.f;
#pragma unroll
  for(int r=0;r<NRELM1;r++) g = fmaf(l[r]*inv, W[r*CH+lane], g);
  float acc=0.f;
  int s=startU[u], e2=startU[u+1];
  for(int p=s;p<e2;p++){
    int id = sortedU[p];
    acc = fmaf(ivals[id], ent[(size_t)icols[id]*CH+lane], acc);
  }
  float res = acc*(1.f+g);
  float nrm = sqrtf(waveReduceSum(res*res));
  float outv = res / fmaxf(nrm, 1e-12f);
  usr_res[(size_t)u*CH+lane] += outv;
  usr[(size_t)u*CH+lane] = outv;
}

// ---------------- entity finalize: l2norm + residual ----------------
__global__ __launch_bounds__(256) void k_entfin(const float* __restrict__ agg,
                                                float* __restrict__ cur,
                                                float* __restrict__ res){
  int wave=threadIdx.x>>6, lane=threadIdx.x&63;
  int r = blockIdx.x*4+wave;
  if(r>=N_ENT) return;
  float v = agg[(size_t)r*CH+lane];
  float nrm = sqrtf(waveReduceSum(v*v));
  float outv = v / fmaxf(nrm, 1e-12f);
  cur[(size_t)r*CH+lane]=outv;
  res[(size_t)r*CH+lane]+=outv;
}

// ---------------- final adj scatter: adj[r,c] += coef * dinv[r]*v*dinv[c] ----------------
__global__ void k_scatter_adj(const int* __restrict__ knn_idx,
                              const float* __restrict__ knn_val,
                              const float* __restrict__ rowsum,
                              float coef, float* __restrict__ adj){
  int i = blockIdx.x*blockDim.x+threadIdx.x;
  if(i>=N_ENT*TOPKC) return;
  int row = i/TOPKC;
  int col = knn_idx[i];
  float v = knn_val[i];
  float dv = coef * v / (sqrtf(rowsum[row]) * sqrtf(rowsum[col]));
  atomicAdd(&adj[(size_t)row*N_ENT+col], dv);
}

extern "C" void kernel_launch(void* const* d_in, const int* in_sizes, int n_in,
                              void* d_out, int out_size, void* d_ws, size_t ws_size,
                              hipStream_t stream){
  const float* user_emb   = (const float*)d_in[0];
  const float* entity_emb = (const float*)d_in[1];
  const int*   edge_index = (const int*)d_in[2];
  const int*   edge_type  = (const int*)d_in[3];
  const int*   inter_idx  = (const int*)d_in[4];
  const float* inter_vals = (const float*)d_in[5];
  const float* W          = (const float*)d_in[6];

  const int* head  = edge_index;
  const int* tail  = edge_index + N_EDGEC;
  const int* irows = inter_idx;
  const int* icols = inter_idx + NNZC;

  float* out     = (float*)d_out;
  float* ent_res = out;
  float* usr_res = out + (size_t)N_ENT*CH;
  float* adj     = out + (size_t)N_ENT*CH + (size_t)N_USR*CH;

  char* wp = (char*)d_ws;
  auto alloc = [&](size_t bytes)->void*{
    void* p = (void*)wp; wp += (bytes+255)/256*256; return p;
  };
  float* cn      = (float*)alloc((size_t)N_ENT*CH*4);
  float* cur_ent = (float*)alloc((size_t)N_ENT*CH*4);
  float* cur_usr = (float*)alloc((size_t)N_USR*CH*4);
  float* agg     = (float*)alloc((size_t)N_ENT*CH*4);
  float* q       = (float*)alloc((size_t)N_ENT*NRELM1*4);
  int*   histE   = (int*)alloc((size_t)N_ENT*4);
  int*   startE  = (int*)alloc((size_t)(N_ENT+1)*4);
  int*   cursorE = (int*)alloc((size_t)N_ENT*4);
  int*   sortedE = (int*)alloc((size_t)N_EDGEC*4);
  int*   histU   = (int*)alloc((size_t)N_USR*4);
  int*   startU  = (int*)alloc((size_t)(N_USR+1)*4);
  int*   cursorU = (int*)alloc((size_t)N_USR*4);
  int*   sortedU = (int*)alloc((size_t)NNZC*4);
  int*   knn_idx0= (int*)alloc((size_t)N_ENT*TOPKC*4);
  float* knn_val0= (float*)alloc((size_t)N_ENT*TOPKC*4);
  float* rowsum0 = (float*)alloc((size_t)N_ENT*4);
  int*   knn_idx1= (int*)alloc((size_t)N_ENT*TOPKC*4);
  float* knn_val1= (float*)alloc((size_t)N_ENT*TOPKC*4);
  float* rowsum1 = (float*)alloc((size_t)N_ENT*4);

  // init
  hipMemsetAsync(histE, 0, (size_t)N_ENT*4, stream);
  hipMemsetAsync(histU, 0, (size_t)N_USR*4, stream);
  hipMemcpyAsync(ent_res, entity_emb, (size_t)N_ENT*CH*4, hipMemcpyDeviceToDevice, stream);
  hipMemcpyAsync(usr_res, user_emb,   (size_t)N_USR*CH*4, hipMemcpyDeviceToDevice, stream);
  hipMemcpyAsync(cur_ent, entity_emb, (size_t)N_ENT*CH*4, hipMemcpyDeviceToDevice, stream);
  hipMemcpyAsync(cur_usr, user_emb,   (size_t)N_USR*CH*4, hipMemcpyDeviceToDevice, stream);

  // counting sorts (edges by head, inter by row) — reused by both hops
  k_hist<<<1024,256,0,stream>>>(head, N_EDGEC, histE);
  k_hist<<<512,256,0,stream>>>(irows, NNZC, histU);
  k_scan<<<1,1024,0,stream>>>(histE, startE, cursorE, N_ENT);
  k_scan<<<1,1024,0,stream>>>(histU, startU, cursorU, N_USR);
  k_scatter_sort<<<1024,256,0,stream>>>(head, N_EDGEC, cursorE, sortedE);
  k_scatter_sort<<<512,256,0,stream>>>(irows, NNZC, cursorU, sortedU);

  dim3 gg(N_ENT/128, N_ENT/128);

  // build_adj #1 on original entity_emb (sim matrix staged in the adj output region)
  k_rownorm<<<N_ENT/4,256,0,stream>>>(entity_emb, cn, N_ENT, 0.f);
  k_gemm_nt<<<gg,256,0,stream>>>(cn, adj);
  k_topk<<<N_ENT/4,256,0,stream>>>(adj, knn_idx0, knn_val0, rowsum0);

  // 2 hops
  for(int hop=0; hop<2; ++hop){
    k_q<<<N_ENT/4,256,0,stream>>>(cur_ent, W, q);
    k_edge_agg<<<N_ENT/4,256,0,stream>>>(tail, edge_type, startE, sortedE,
                                         cur_ent, W, q, agg);
    k_user<<<N_USR/4,256,0,stream>>>(icols, inter_vals, startU, sortedU,
                                     cur_ent, W, cur_usr, usr_res);
    k_entfin<<<N_ENT/4,256,0,stream>>>(agg, cur_ent, ent_res);
  }

  // build_adj #2 on entity_res_emb
  k_rownorm<<<N_ENT/4,256,0,stream>>>(ent_res, cn, N_ENT, 0.f);
  k_gemm_nt<<<gg,256,0,stream>>>(cn, adj);
  k_topk<<<N_ENT/4,256,0,stream>>>(adj, knn_idx1, knn_val1, rowsum1);

  // item_adj = 0.5*new + 0.5*origin, materialized dense
  hipMemsetAsync(adj, 0, (size_t)N_ENT*N_ENT*4, stream);
  int nsc = (N_ENT*TOPKC+255)/256;
  k_scatter_adj<<<nsc,256,0,stream>>>(knn_idx1, knn_val1, rowsum1, 0.5f, adj);
  k_scatter_adj<<<nsc,256,0,stream>>>(knn_idx0, knn_val0, rowsum0, 0.5f, adj);
}

// Round 3
// 1083.709 us; speedup vs baseline: 1.4980x; 1.2689x over previous
//
#include <hip/hip_runtime.h>
#include <hip/hip_bf16.h>

#define N_ENT   8192
#define N_USR   16384
#define CH      64
#define N_EDGEC 1000000
#define NNZC    500000
#define TOPKC   10
#define NRELM1  8

static __device__ __forceinline__ float waveReduceSum(float v){
#pragma unroll
  for(int o=1;o<64;o<<=1) v += __shfl_xor(v,o,64);
  return v;
}
static __device__ __forceinline__ float waveReduceMax(float v){
#pragma unroll
  for(int o=1;o<64;o<<=1) v = fmaxf(v, __shfl_xor(v,o,64));
  return v;
}

// ---------------- sorting (counting sort by segment key) ----------------
__global__ void k_hist(const int* __restrict__ keys, int n, int* __restrict__ hist){
  int i = blockIdx.x*blockDim.x + threadIdx.x;
  int stride = gridDim.x*blockDim.x;
  for(; i<n; i+=stride) atomicAdd(&hist[keys[i]], 1);
}

__global__ __launch_bounds__(1024) void k_scan(const int* __restrict__ hist,
                                               int* __restrict__ start,
                                               int* __restrict__ cursor, int n){
  __shared__ int part[1024];
  int t = threadIdx.x;
  int chunk = n/1024;
  int base = t*chunk;
  int s = 0;
  for(int i=0;i<chunk;i++) s += hist[base+i];
  part[t] = s; __syncthreads();
  for(int off=1; off<1024; off<<=1){
    int v = (t>=off) ? part[t-off] : 0;
    __syncthreads();
    part[t] += v;
    __syncthreads();
  }
  int run = (t==0) ? 0 : part[t-1];
  for(int i=0;i<chunk;i++){
    start[base+i] = run; cursor[base+i] = run;
    run += hist[base+i];
  }
  if(t==1023) start[n] = run;
}

// fused: scatter edges by head, writing packed (tail | rel<<13) at sorted position
__global__ void k_scatter_sortE(const int* __restrict__ head,
                                const int* __restrict__ tail,
                                const int* __restrict__ etype, int n,
                                int* __restrict__ cursor, int* __restrict__ trS){
  int i = blockIdx.x*blockDim.x + threadIdx.x;
  int stride = gridDim.x*blockDim.x;
  for(; i<n; i+=stride){
    int pos = atomicAdd(&cursor[head[i]], 1);
    trS[pos] = (tail[i] & 8191) | ((etype[i]-1)<<13);
  }
}

// fused: scatter interactions by row, writing col + val at sorted position
__global__ void k_scatter_sortU(const int* __restrict__ irows,
                                const int* __restrict__ icols,
                                const float* __restrict__ ivals, int n,
                                int* __restrict__ cursor,
                                int* __restrict__ icolsS, float* __restrict__ ivalsS){
  int i = blockIdx.x*blockDim.x + threadIdx.x;
  int stride = gridDim.x*blockDim.x;
  for(; i<n; i+=stride){
    int pos = atomicAdd(&cursor[irows[i]], 1);
    icolsS[pos] = icols[i];
    ivalsS[pos] = ivals[i];
  }
}

// ---------------- row normalize (cn and l2norm) ----------------
__global__ __launch_bounds__(256) void k_rownorm(const float* __restrict__ in,
                                                 float* __restrict__ out,
                                                 int rows, float eps){
  int wave = threadIdx.x>>6, lane = threadIdx.x&63;
  int r = blockIdx.x*4 + wave;
  if(r>=rows) return;
  float v = in[(size_t)r*CH+lane];
  float ss = waveReduceSum(v*v);
  float nrm = sqrtf(ss);
  out[(size_t)r*CH+lane] = v / fmaxf(nrm, eps);
}

// ---------------- sim GEMM: C = A * A^T, K=64, f32 vector ALU ----------------
__global__ __launch_bounds__(256,2) void k_gemm_nt(const float* __restrict__ A,
                                                   float* __restrict__ C){
  __shared__ float As[CH][132];
  __shared__ float Bs[CH][132];
  const int tid = threadIdx.x;
  const int bi = blockIdx.y*128, bj = blockIdx.x*128;
#pragma unroll
  for(int k=0;k<8;k++){
    int idx = tid + k*256;
    int row = idx>>4;
    int c4  = (idx&15)*4;
    float4 va = ((const float4*)(A + (size_t)(bi+row)*CH))[c4>>2];
    As[c4+0][row]=va.x; As[c4+1][row]=va.y; As[c4+2][row]=va.z; As[c4+3][row]=va.w;
    float4 vb = ((const float4*)(A + (size_t)(bj+row)*CH))[c4>>2];
    Bs[c4+0][row]=vb.x; Bs[c4+1][row]=vb.y; Bs[c4+2][row]=vb.z; Bs[c4+3][row]=vb.w;
  }
  __syncthreads();
  const int tx = tid&15, ty = tid>>4;
  float acc[8][8];
#pragma unroll
  for(int i=0;i<8;i++)
#pragma unroll
    for(int j=0;j<8;j++) acc[i][j]=0.f;
#pragma unroll 8
  for(int k=0;k<CH;k++){
    float4 a0 = *(const float4*)&As[k][ty*8];
    float4 a1 = *(const float4*)&As[k][ty*8+4];
    float4 b0 = *(const float4*)&Bs[k][tx*8];
    float4 b1 = *(const float4*)&Bs[k][tx*8+4];
    float a[8]={a0.x,a0.y,a0.z,a0.w,a1.x,a1.y,a1.z,a1.w};
    float b[8]={b0.x,b0.y,b0.z,b0.w,b1.x,b1.y,b1.z,b1.w};
#pragma unroll
    for(int i=0;i<8;i++)
#pragma unroll
      for(int j=0;j<8;j++) acc[i][j] = fmaf(a[i], b[j], acc[i][j]);
  }
#pragma unroll
  for(int i=0;i<8;i++){
    float4 o0 = {acc[i][0],acc[i][1],acc[i][2],acc[i][3]};
    float4 o1 = {acc[i][4],acc[i][5],acc[i][6],acc[i][7]};
    float* crow = C + (size_t)(bi+ty*8+i)*N_ENT + bj + tx*8;
    *(float4*)crow = o0;
    *((float4*)crow+1) = o1;
  }
}

// ---------------- per-row top-k: one wave per row, register-only ----------------
__global__ __launch_bounds__(256) void k_topk(const float* __restrict__ S,
                                              int* __restrict__ knn_idx,
                                              float* __restrict__ knn_val,
                                              float* __restrict__ rowsum){
  const int wave = threadIdx.x>>6, lane = threadIdx.x&63;
  const int row = blockIdx.x*4 + wave;
  if(row>=N_ENT) return;
  const float4* s4 = (const float4*)(S + (size_t)row*N_ENT);

  unsigned long long loc[TOPKC];
#pragma unroll
  for(int i=0;i<TOPKC;i++) loc[i]=0ull;

#pragma unroll 4
  for(int it=0; it<N_ENT/(64*4); ++it){
    int vi = it*64 + lane;
    float4 v = s4[vi];
    int c0 = vi*4;
    float vv[4] = {v.x, v.y, v.z, v.w};
#pragma unroll
    for(int j=0;j<4;j++){
      unsigned u = __float_as_uint(vv[j]);
      u = (u & 0x80000000u) ? ~u : (u | 0x80000000u);
      unsigned long long key = ((unsigned long long)u<<32)
                             | (unsigned long long)(0xFFFFFFFFu - (unsigned)(c0+j));
      if(key > loc[TOPKC-1]){
        unsigned long long t = key;
#pragma unroll
        for(int z=0; z<TOPKC; ++z){
          if(t > loc[z]){ unsigned long long tmp=loc[z]; loc[z]=t; t=tmp; }
        }
      }
    }
  }

  float rs = 0.f;
  for(int sel=0; sel<TOPKC; ++sel){
    unsigned long long m = loc[0];
#pragma unroll
    for(int o=1;o<64;o<<=1){
      unsigned long long other = __shfl_xor(m, o, 64);
      if(other > m) m = other;
    }
    if(loc[0] == m){
#pragma unroll
      for(int z=0;z<TOPKC-1;++z) loc[z]=loc[z+1];
      loc[TOPKC-1]=0ull;
    }
    if(lane==0){
      unsigned mk = (unsigned)(m>>32);
      unsigned uo = (mk & 0x80000000u) ? (mk ^ 0x80000000u) : ~mk;
      float v = __uint_as_float(uo);
      int col = (int)(0xFFFFFFFFu - (unsigned)(m & 0xFFFFFFFFu));
      knn_idx[row*TOPKC+sel] = col;
      knn_val[row*TOPKC+sel] = v;
      rs += v;
    }
  }
  if(lane==0) rowsum[row] = rs;
}

// ---------------- q[i][r] = ||ent_i * W_r||^2 ----------------
__global__ __launch_bounds__(256) void k_q(const float* __restrict__ ent,
                                           const float* __restrict__ W,
                                           float* __restrict__ q){
  int wave=threadIdx.x>>6, lane=threadIdx.x&63;
  int r = blockIdx.x*4+wave;
  if(r>=N_ENT) return;
  float x = ent[(size_t)r*CH+lane];
#pragma unroll
  for(int rel=0; rel<NRELM1; rel++){
    float tt = x*W[rel*CH+lane];
    float s = waveReduceSum(tt*tt);
    if(lane==0) q[r*NRELM1+rel]=s;
  }
}

// ---------------- per-head edge aggregation (contiguous sorted arrays) ----------------
__global__ __launch_bounds__(256) void k_edge_agg(
    const int* __restrict__ trS, const int* __restrict__ startE,
    const float* __restrict__ ent, const float* __restrict__ W,
    const float* __restrict__ q, float* __restrict__ wbuf,
    float* __restrict__ agg){
  int wave=threadIdx.x>>6, lane=threadIdx.x&63;
  int h = blockIdx.x*4+wave;
  if(h>=N_ENT) return;
  int s = startE[h], e2 = startE[h+1];

  float qh[NRELM1];
#pragma unroll
  for(int r=0;r<NRELM1;r++) qh[r] = q[h*NRELM1+r];

  // pass 1: att -> wbuf, track max (att >= 0 always)
  float mx = 0.f;
  for(int p=s+lane; p<e2; p+=64){
    int tr = trS[p];
    int tl = tr & 8191, r = tr>>13;
    float att = qh[r]*q[tl*NRELM1+r];
    wbuf[p] = att;
    mx = fmaxf(mx, att);
  }
  mx = waveReduceMax(mx);

  // pass 2: exp in place, sum
  float dn = 0.f;
  for(int p=s+lane; p<e2; p+=64){
    float e = expf(wbuf[p]-mx);
    wbuf[p] = e;
    dn += e;
  }
  dn = waveReduceSum(dn);
  float inv = (dn>0.f) ? 1.f/dn : 0.f;

  // pass 3: weighted aggregate; W rows preloaded per lane
  float wr[NRELM1];
#pragma unroll
  for(int r=0;r<NRELM1;r++) wr[r] = W[r*CH+lane];
  float acc = 0.f;
  for(int p=s; p<e2; p++){
    int tr = trS[p];                 // broadcast load
    int tl = tr & 8191, r = tr>>13;
    float wgt = wbuf[p]*inv;         // broadcast load
    acc = fmaf(wgt*wr[r], ent[(size_t)tl*CH+lane], acc);
  }
  agg[(size_t)h*CH+lane] = acc;
}

// ---------------- per-user: sparse agg + gated score + l2norm + residual ----------------
__global__ __launch_bounds__(256) void k_user(
    const int* __restrict__ icolsS, const float* __restrict__ ivalsS,
    const int* __restrict__ startU,
    const float* __restrict__ ent, const float* __restrict__ W,
    float* __restrict__ usr, float* __restrict__ usr_res){
  int wave=threadIdx.x>>6, lane=threadIdx.x&63;
  int u = blockIdx.x*4+wave;
  if(u>=N_USR) return;
  float ue = usr[(size_t)u*CH+lane];
  float l[NRELM1];
#pragma unroll
  for(int r=0;r<NRELM1;r++) l[r] = waveReduceSum(ue*W[r*CH+lane]);
  float lm = l[0];
#pragma unroll
  for(int r=1;r<NRELM1;r++) lm = fmaxf(lm,l[r]);
  float se=0.f;
#pragma unroll
  for(int r=0;r<NRELM1;r++){ l[r]=expf(l[r]-lm); se+=l[r]; }
  float inv = 1.f/se;
  float g = 0.f;
#pragma unroll
  for(int r=0;r<NRELM1;r++) g = fmaf(l[r]*inv, W[r*CH+lane], g);
  float acc=0.f;
  int s=startU[u], e2=startU[u+1];
  for(int p=s;p<e2;p++){
    acc = fmaf(ivalsS[p], ent[(size_t)icolsS[p]*CH+lane], acc);
  }
  float res = acc*(1.f+g);
  float nrm = sqrtf(waveReduceSum(res*res));
  float outv = res / fmaxf(nrm, 1e-12f);
  usr_res[(size_t)u*CH+lane] += outv;
  usr[(size_t)u*CH+lane] = outv;
}

// ---------------- entity finalize: l2norm + residual ----------------
__global__ __launch_bounds__(256) void k_entfin(const float* __restrict__ agg,
                                                float* __restrict__ cur,
                                                float* __restrict__ res){
  int wave=threadIdx.x>>6, lane=threadIdx.x&63;
  int r = blockIdx.x*4+wave;
  if(r>=N_ENT) return;
  float v = agg[(size_t)r*CH+lane];
  float nrm = sqrtf(waveReduceSum(v*v));
  float outv = v / fmaxf(nrm, 1e-12f);
  cur[(size_t)r*CH+lane]=outv;
  res[(size_t)r*CH+lane]+=outv;
}

// ---------------- final adj scatter ----------------
__global__ void k_scatter_adj(const int* __restrict__ knn_idx,
                              const float* __restrict__ knn_val,
                              const float* __restrict__ rowsum,
                              float coef, float* __restrict__ adj){
  int i = blockIdx.x*blockDim.x+threadIdx.x;
  if(i>=N_ENT*TOPKC) return;
  int row = i/TOPKC;
  int col = knn_idx[i];
  float v = knn_val[i];
  float dv = coef * v / (sqrtf(rowsum[row]) * sqrtf(rowsum[col]));
  atomicAdd(&adj[(size_t)row*N_ENT+col], dv);
}

extern "C" void kernel_launch(void* const* d_in, const int* in_sizes, int n_in,
                              void* d_out, int out_size, void* d_ws, size_t ws_size,
                              hipStream_t stream){
  const float* user_emb   = (const float*)d_in[0];
  const float* entity_emb = (const float*)d_in[1];
  const int*   edge_index = (const int*)d_in[2];
  const int*   edge_type  = (const int*)d_in[3];
  const int*   inter_idx  = (const int*)d_in[4];
  const float* inter_vals = (const float*)d_in[5];
  const float* W          = (const float*)d_in[6];

  const int* head  = edge_index;
  const int* tail  = edge_index + N_EDGEC;
  const int* irows = inter_idx;
  const int* icols = inter_idx + NNZC;

  float* out     = (float*)d_out;
  float* ent_res = out;
  float* usr_res = out + (size_t)N_ENT*CH;
  float* adj     = out + (size_t)N_ENT*CH + (size_t)N_USR*CH;

  char* wp = (char*)d_ws;
  auto alloc = [&](size_t bytes)->void*{
    void* p = (void*)wp; wp += (bytes+255)/256*256; return p;
  };
  float* cn      = (float*)alloc((size_t)N_ENT*CH*4);
  float* cur_ent = (float*)alloc((size_t)N_ENT*CH*4);
  float* cur_usr = (float*)alloc((size_t)N_USR*CH*4);
  float* agg     = (float*)alloc((size_t)N_ENT*CH*4);
  float* q       = (float*)alloc((size_t)N_ENT*NRELM1*4);
  int*   histE   = (int*)alloc((size_t)N_ENT*4);
  int*   startE  = (int*)alloc((size_t)(N_ENT+1)*4);
  int*   cursorE = (int*)alloc((size_t)N_ENT*4);
  int*   trS     = (int*)alloc((size_t)N_EDGEC*4);
  int*   histU   = (int*)alloc((size_t)N_USR*4);
  int*   startU  = (int*)alloc((size_t)(N_USR+1)*4);
  int*   cursorU = (int*)alloc((size_t)N_USR*4);
  int*   icolsS  = (int*)alloc((size_t)NNZC*4);
  float* ivalsS  = (float*)alloc((size_t)NNZC*4);
  int*   knn_idx0= (int*)alloc((size_t)N_ENT*TOPKC*4);
  float* knn_val0= (float*)alloc((size_t)N_ENT*TOPKC*4);
  float* rowsum0 = (float*)alloc((size_t)N_ENT*4);
  int*   knn_idx1= (int*)alloc((size_t)N_ENT*TOPKC*4);
  float* knn_val1= (float*)alloc((size_t)N_ENT*TOPKC*4);
  float* rowsum1 = (float*)alloc((size_t)N_ENT*4);

  // wbuf for edge softmax lives in the adj output region (256MB, idle during hops)
  float* wbuf = adj;

  // init
  hipMemsetAsync(histE, 0, (size_t)N_ENT*4, stream);
  hipMemsetAsync(histU, 0, (size_t)N_USR*4, stream);
  hipMemcpyAsync(ent_res, entity_emb, (size_t)N_ENT*CH*4, hipMemcpyDeviceToDevice, stream);
  hipMemcpyAsync(usr_res, user_emb,   (size_t)N_USR*CH*4, hipMemcpyDeviceToDevice, stream);
  hipMemcpyAsync(cur_ent, entity_emb, (size_t)N_ENT*CH*4, hipMemcpyDeviceToDevice, stream);
  hipMemcpyAsync(cur_usr, user_emb,   (size_t)N_USR*CH*4, hipMemcpyDeviceToDevice, stream);

  // counting sorts with fused payload gather (edges by head, inter by row)
  k_hist<<<1024,256,0,stream>>>(head, N_EDGEC, histE);
  k_hist<<<512,256,0,stream>>>(irows, NNZC, histU);
  k_scan<<<1,1024,0,stream>>>(histE, startE, cursorE, N_ENT);
  k_scan<<<1,1024,0,stream>>>(histU, startU, cursorU, N_USR);
  k_scatter_sortE<<<1024,256,0,stream>>>(head, tail, edge_type, N_EDGEC, cursorE, trS);
  k_scatter_sortU<<<512,256,0,stream>>>(irows, icols, inter_vals, NNZC, cursorU, icolsS, ivalsS);

  dim3 gg(N_ENT/128, N_ENT/128);

  // build_adj #1 on original entity_emb (sim matrix staged in the adj output region)
  k_rownorm<<<N_ENT/4,256,0,stream>>>(entity_emb, cn, N_ENT, 0.f);
  k_gemm_nt<<<gg,256,0,stream>>>(cn, adj);
  k_topk<<<N_ENT/4,256,0,stream>>>(adj, knn_idx0, knn_val0, rowsum0);

  // 2 hops
  for(int hop=0; hop<2; ++hop){
    k_q<<<N_ENT/4,256,0,stream>>>(cur_ent, W, q);
    k_edge_agg<<<N_ENT/4,256,0,stream>>>(trS, startE, cur_ent, W, q, wbuf, agg);
    k_user<<<N_USR/4,256,0,stream>>>(icolsS, ivalsS, startU, cur_ent, W, cur_usr, usr_res);
    k_entfin<<<N_ENT/4,256,0,stream>>>(agg, cur_ent, ent_res);
  }

  // build_adj #2 on entity_res_emb
  k_rownorm<<<N_ENT/4,256,0,stream>>>(ent_res, cn, N_ENT, 0.f);
  k_gemm_nt<<<gg,256,0,stream>>>(cn, adj);
  k_topk<<<N_ENT/4,256,0,stream>>>(adj, knn_idx1, knn_val1, rowsum1);

  // item_adj = 0.5*new + 0.5*origin, materialized dense
  hipMemsetAsync(adj, 0, (size_t)N_ENT*N_ENT*4, stream);
  int nsc = (N_ENT*TOPKC+255)/256;
  k_scatter_adj<<<nsc,256,0,stream>>>(knn_idx1, knn_val1, rowsum1, 0.5f, adj);
  k_scatter_adj<<<nsc,256,0,stream>>>(knn_idx0, knn_val0, rowsum0, 0.5f, adj);
}

// Round 4
// 1024.312 us; speedup vs baseline: 1.5848x; 1.0580x over previous
//
#include <hip/hip_runtime.h>
#include <hip/hip_bf16.h>

#define N_ENT   8192
#define N_USR   16384
#define CH      64
#define N_EDGEC 1000000
#define NNZC    500000
#define TOPKC   10
#define NRELM1  8

static __device__ __forceinline__ float waveReduceSum(float v){
#pragma unroll
  for(int o=1;o<64;o<<=1) v += __shfl_xor(v,o,64);
  return v;
}
static __device__ __forceinline__ float waveReduceMax(float v){
#pragma unroll
  for(int o=1;o<64;o<<=1) v = fmaxf(v, __shfl_xor(v,o,64));
  return v;
}
static __device__ __forceinline__ int waveReduceMaxI(int v){
#pragma unroll
  for(int o=1;o<64;o<<=1){ int t=__shfl_xor(v,o,64); v = t>v? t: v; }
  return v;
}
static __device__ __forceinline__ unsigned long long u64max(unsigned long long a, unsigned long long b){
  return a>b? a: b;
}
static __device__ __forceinline__ unsigned mapf(float v){
  unsigned u = __float_as_uint(v);
  return (u & 0x80000000u) ? ~u : (u | 0x80000000u);
}

// ---------------- sorting (counting sort by segment key) ----------------
__global__ void k_hist(const int* __restrict__ keys, int n, int* __restrict__ hist){
  int i = blockIdx.x*blockDim.x + threadIdx.x;
  int stride = gridDim.x*blockDim.x;
  for(; i<n; i+=stride) atomicAdd(&hist[keys[i]], 1);
}

__global__ __launch_bounds__(1024) void k_scan(const int* __restrict__ hist,
                                               int* __restrict__ start,
                                               int* __restrict__ cursor, int n){
  __shared__ int part[1024];
  int t = threadIdx.x;
  int chunk = n/1024;
  int base = t*chunk;
  int s = 0;
  for(int i=0;i<chunk;i++) s += hist[base+i];
  part[t] = s; __syncthreads();
  for(int off=1; off<1024; off<<=1){
    int v = (t>=off) ? part[t-off] : 0;
    __syncthreads();
    part[t] += v;
    __syncthreads();
  }
  int run = (t==0) ? 0 : part[t-1];
  for(int i=0;i<chunk;i++){
    start[base+i] = run; cursor[base+i] = run;
    run += hist[base+i];
  }
  if(t==1023) start[n] = run;
}

// fused: scatter edges by head, writing packed (tail | rel<<13) at sorted position
__global__ void k_scatter_sortE(const int* __restrict__ head,
                                const int* __restrict__ tail,
                                const int* __restrict__ etype, int n,
                                int* __restrict__ cursor, int* __restrict__ trS){
  int i = blockIdx.x*blockDim.x + threadIdx.x;
  int stride = gridDim.x*blockDim.x;
  for(; i<n; i+=stride){
    int pos = atomicAdd(&cursor[head[i]], 1);
    trS[pos] = (tail[i] & 8191) | ((etype[i]-1)<<13);
  }
}

// fused: scatter interactions by row, writing col + val at sorted position
__global__ void k_scatter_sortU(const int* __restrict__ irows,
                                const int* __restrict__ icols,
                                const float* __restrict__ ivals, int n,
                                int* __restrict__ cursor,
                                int* __restrict__ icolsS, float* __restrict__ ivalsS){
  int i = blockIdx.x*blockDim.x + threadIdx.x;
  int stride = gridDim.x*blockDim.x;
  for(; i<n; i+=stride){
    int pos = atomicAdd(&cursor[irows[i]], 1);
    icolsS[pos] = icols[i];
    ivalsS[pos] = ivals[i];
  }
}

// ---------------- row normalize (cn and l2norm) ----------------
__global__ __launch_bounds__(256) void k_rownorm(const float* __restrict__ in,
                                                 float* __restrict__ out,
                                                 int rows, float eps){
  int wave = threadIdx.x>>6, lane = threadIdx.x&63;
  int r = blockIdx.x*4 + wave;
  if(r>=rows) return;
  float v = in[(size_t)r*CH+lane];
  float ss = waveReduceSum(v*v);
  float nrm = sqrtf(ss);
  out[(size_t)r*CH+lane] = v / fmaxf(nrm, eps);
}

// ---------------- sim GEMM: C = A * A^T, K=64, f32 vector ALU ----------------
__global__ __launch_bounds__(256,2) void k_gemm_nt(const float* __restrict__ A,
                                                   float* __restrict__ C){
  __shared__ float As[CH][132];
  __shared__ float Bs[CH][132];
  const int tid = threadIdx.x;
  const int bi = blockIdx.y*128, bj = blockIdx.x*128;
#pragma unroll
  for(int k=0;k<8;k++){
    int idx = tid + k*256;
    int row = idx>>4;
    int c4  = (idx&15)*4;
    float4 va = ((const float4*)(A + (size_t)(bi+row)*CH))[c4>>2];
    As[c4+0][row]=va.x; As[c4+1][row]=va.y; As[c4+2][row]=va.z; As[c4+3][row]=va.w;
    float4 vb = ((const float4*)(A + (size_t)(bj+row)*CH))[c4>>2];
    Bs[c4+0][row]=vb.x; Bs[c4+1][row]=vb.y; Bs[c4+2][row]=vb.z; Bs[c4+3][row]=vb.w;
  }
  __syncthreads();
  const int tx = tid&15, ty = tid>>4;
  float acc[8][8];
#pragma unroll
  for(int i=0;i<8;i++)
#pragma unroll
    for(int j=0;j<8;j++) acc[i][j]=0.f;
#pragma unroll 8
  for(int k=0;k<CH;k++){
    float4 a0 = *(const float4*)&As[k][ty*8];
    float4 a1 = *(const float4*)&As[k][ty*8+4];
    float4 b0 = *(const float4*)&Bs[k][tx*8];
    float4 b1 = *(const float4*)&Bs[k][tx*8+4];
    float a[8]={a0.x,a0.y,a0.z,a0.w,a1.x,a1.y,a1.z,a1.w};
    float b[8]={b0.x,b0.y,b0.z,b0.w,b1.x,b1.y,b1.z,b1.w};
#pragma unroll
    for(int i=0;i<8;i++)
#pragma unroll
      for(int j=0;j<8;j++) acc[i][j] = fmaf(a[i], b[j], acc[i][j]);
  }
#pragma unroll
  for(int i=0;i<8;i++){
    float4 o0 = {acc[i][0],acc[i][1],acc[i][2],acc[i][3]};
    float4 o1 = {acc[i][4],acc[i][5],acc[i][6],acc[i][7]};
    float* crow = C + (size_t)(bi+ty*8+i)*N_ENT + bj + tx*8;
    *(float4*)crow = o0;
    *((float4*)crow+1) = o1;
  }
}

// ---------------- per-row top-k: radix-select, one wave per row ----------------
// key = mapped_float<<32 | (0xFFFFFFFF - col): larger wins; ties -> smaller col.
#define CANDCAP 256
__global__ __launch_bounds__(64) void k_topk(const float* __restrict__ S,
                                             int* __restrict__ knn_idx,
                                             float* __restrict__ knn_val,
                                             float* __restrict__ rowsum){
  const int row = blockIdx.x;
  const int lane = threadIdx.x;
  const float4* s4 = (const float4*)(S + (size_t)row*N_ENT);

  __shared__ int hist[2048];
  __shared__ unsigned long long cand[CANDCAP];
  __shared__ int cnt;
#pragma unroll
  for(int i=lane;i<2048;i+=64) hist[i]=0;
  if(lane==0) cnt=0;
  __syncthreads();

  // pass 1: histogram of mapped>>21 (sign+exp+2mant bits)
  for(int it=0; it<N_ENT/256; ++it){
    float4 v = s4[it*64+lane];
    atomicAdd(&hist[mapf(v.x)>>21],1);
    atomicAdd(&hist[mapf(v.y)>>21],1);
    atomicAdd(&hist[mapf(v.z)>>21],1);
    atomicAdd(&hist[mapf(v.w)>>21],1);
  }
  __syncthreads();

  // find cutoff bin B: smallest bin with cum(>=B) >= TOPKC
  int base = lane*32;
  int s = 0;
#pragma unroll
  for(int j=0;j<32;j++) s += hist[base+j];
  int ss = s;                                   // inclusive suffix over lanes
#pragma unroll
  for(int off=1; off<64; off<<=1){
    int t = __shfl_down(ss, off, 64);
    if(lane+off<64) ss += t;
  }
  int above = ss - s;                           // cum of lanes > this one
  int B_local = 0;
  if(ss >= TOPKC && above < TOPKC){
    int running = above;
    for(int j=31;j>=0;--j){
      running += hist[base+j];
      if(running >= TOPKC){ B_local = base+j; break; }
    }
  }
  int B = waveReduceMaxI(B_local);
  unsigned thr = (unsigned)B << 21;

  // pass 2: collect candidates (mapped >= thr) into LDS
  for(int it=0; it<N_ENT/256; ++it){
    int vi = it*64+lane;
    float4 v = s4[vi];
    int c0 = vi*4;
    float vv[4] = {v.x,v.y,v.z,v.w};
#pragma unroll
    for(int j=0;j<4;j++){
      unsigned m = mapf(vv[j]);
      if(m >= thr){
        int pos = atomicAdd(&cnt,1);
        if(pos < CANDCAP)
          cand[pos] = ((unsigned long long)m<<32)
                    | (unsigned long long)(0xFFFFFFFFu - (unsigned)(c0+j));
      }
    }
  }
  __syncthreads();
  int n = cnt;

  if(n <= CANDCAP){
    // select top-10 from <=256 candidates: 4 slots/lane + 10 shfl-max rounds
    unsigned long long c0 = (lane      < n) ? cand[lane]       : 0ull;
    unsigned long long c1 = (lane+64   < n) ? cand[lane+64]    : 0ull;
    unsigned long long c2 = (lane+128  < n) ? cand[lane+128]   : 0ull;
    unsigned long long c3 = (lane+192  < n) ? cand[lane+192]   : 0ull;
    float rs = 0.f;
    for(int sel=0; sel<TOPKC; ++sel){
      unsigned long long m = u64max(u64max(c0,c1), u64max(c2,c3));
#pragma unroll
      for(int o=1;o<64;o<<=1) m = u64max(m, __shfl_xor(m,o,64));
      if(c0==m) c0=0ull; else if(c1==m) c1=0ull;
      else if(c2==m) c2=0ull; else if(c3==m) c3=0ull;
      if(lane==0){
        unsigned mk = (unsigned)(m>>32);
        unsigned uo = (mk & 0x80000000u) ? (mk ^ 0x80000000u) : ~mk;
        float v = __uint_as_float(uo);
        int col = (int)(0xFFFFFFFFu - (unsigned)(m & 0xFFFFFFFFu));
        knn_idx[row*TOPKC+sel] = col;
        knn_val[row*TOPKC+sel] = v;
        rs += v;
      }
    }
    if(lane==0) rowsum[row] = rs;
  } else {
    // pathological fallback: exact register insertion scan (legacy path)
    unsigned long long loc[TOPKC];
#pragma unroll
    for(int i=0;i<TOPKC;i++) loc[i]=0ull;
    for(int it=0; it<N_ENT/256; ++it){
      int vi = it*64+lane;
      float4 v = s4[vi];
      int c0i = vi*4;
      float vv[4] = {v.x,v.y,v.z,v.w};
#pragma unroll
      for(int j=0;j<4;j++){
        unsigned u = mapf(vv[j]);
        unsigned long long key = ((unsigned long long)u<<32)
                               | (unsigned long long)(0xFFFFFFFFu - (unsigned)(c0i+j));
        if(key > loc[TOPKC-1]){
          unsigned long long t = key;
#pragma unroll
          for(int z=0; z<TOPKC; ++z){
            if(t > loc[z]){ unsigned long long tmp=loc[z]; loc[z]=t; t=tmp; }
          }
        }
      }
    }
    float rs = 0.f;
    for(int sel=0; sel<TOPKC; ++sel){
      unsigned long long m = loc[0];
#pragma unroll
      for(int o=1;o<64;o<<=1) m = u64max(m, __shfl_xor(m,o,64));
      if(loc[0] == m){
#pragma unroll
        for(int z=0;z<TOPKC-1;++z) loc[z]=loc[z+1];
        loc[TOPKC-1]=0ull;
      }
      if(lane==0){
        unsigned mk = (unsigned)(m>>32);
        unsigned uo = (mk & 0x80000000u) ? (mk ^ 0x80000000u) : ~mk;
        float v = __uint_as_float(uo);
        int col = (int)(0xFFFFFFFFu - (unsigned)(m & 0xFFFFFFFFu));
        knn_idx[row*TOPKC+sel] = col;
        knn_val[row*TOPKC+sel] = v;
        rs += v;
      }
    }
    if(lane==0) rowsum[row] = rs;
  }
}

// ---------------- q[i][r] = ||ent_i * W_r||^2 ----------------
__global__ __launch_bounds__(256) void k_q(const float* __restrict__ ent,
                                           const float* __restrict__ W,
                                           float* __restrict__ q){
  int wave=threadIdx.x>>6, lane=threadIdx.x&63;
  int r = blockIdx.x*4+wave;
  if(r>=N_ENT) return;
  float x = ent[(size_t)r*CH+lane];
#pragma unroll
  for(int rel=0; rel<NRELM1; rel++){
    float tt = x*W[rel*CH+lane];
    float s = waveReduceSum(tt*tt);
    if(lane==0) q[r*NRELM1+rel]=s;
  }
}

// ---------------- per-head edge aggregation (contiguous sorted arrays) ----------------
__global__ __launch_bounds__(256) void k_edge_agg(
    const int* __restrict__ trS, const int* __restrict__ startE,
    const float* __restrict__ ent, const float* __restrict__ W,
    const float* __restrict__ q, float* __restrict__ wbuf,
    float* __restrict__ agg){
  int wave=threadIdx.x>>6, lane=threadIdx.x&63;
  int h = blockIdx.x*4+wave;
  if(h>=N_ENT) return;
  int s = startE[h], e2 = startE[h+1];

  float qh[NRELM1];
#pragma unroll
  for(int r=0;r<NRELM1;r++) qh[r] = q[h*NRELM1+r];

  float mx = 0.f;
  for(int p=s+lane; p<e2; p+=64){
    int tr = trS[p];
    int tl = tr & 8191, r = tr>>13;
    float att = qh[r]*q[tl*NRELM1+r];
    wbuf[p] = att;
    mx = fmaxf(mx, att);
  }
  mx = waveReduceMax(mx);

  float dn = 0.f;
  for(int p=s+lane; p<e2; p+=64){
    float e = expf(wbuf[p]-mx);
    wbuf[p] = e;
    dn += e;
  }
  dn = waveReduceSum(dn);
  float inv = (dn>0.f) ? 1.f/dn : 0.f;

  float wr[NRELM1];
#pragma unroll
  for(int r=0;r<NRELM1;r++) wr[r] = W[r*CH+lane];
  float acc = 0.f;
  for(int p=s; p<e2; p++){
    int tr = trS[p];
    int tl = tr & 8191, r = tr>>13;
    float wgt = wbuf[p]*inv;
    acc = fmaf(wgt*wr[r], ent[(size_t)tl*CH+lane], acc);
  }
  agg[(size_t)h*CH+lane] = acc;
}

// ---------------- per-user: sparse agg + gated score + l2norm + residual ----------------
__global__ __launch_bounds__(256) void k_user(
    const int* __restrict__ icolsS, const float* __restrict__ ivalsS,
    const int* __restrict__ startU,
    const float* __restrict__ ent, const float* __restrict__ W,
    float* __restrict__ usr, float* __restrict__ usr_res){
  int wave=threadIdx.x>>6, lane=threadIdx.x&63;
  int u = blockIdx.x*4+wave;
  if(u>=N_USR) return;
  float ue = usr[(size_t)u*CH+lane];
  float l[NRELM1];
#pragma unroll
  for(int r=0;r<NRELM1;r++) l[r] = waveReduceSum(ue*W[r*CH+lane]);
  float lm = l[0];
#pragma unroll
  for(int r=1;r<NRELM1;r++) lm = fmaxf(lm,l[r]);
  float se=0.f;
#pragma unroll
  for(int r=0;r<NRELM1;r++){ l[r]=expf(l[r]-lm); se+=l[r]; }
  float inv = 1.f/se;
  float g = 0.f;
#pragma unroll
  for(int r=0;r<NRELM1;r++) g = fmaf(l[r]*inv, W[r*CH+lane], g);
  float acc=0.f;
  int s=startU[u], e2=startU[u+1];
  for(int p=s;p<e2;p++){
    acc = fmaf(ivalsS[p], ent[(size_t)icolsS[p]*CH+lane], acc);
  }
  float res = acc*(1.f+g);
  float nrm = sqrtf(waveReduceSum(res*res));
  float outv = res / fmaxf(nrm, 1e-12f);
  usr_res[(size_t)u*CH+lane] += outv;
  usr[(size_t)u*CH+lane] = outv;
}

// ---------------- entity finalize: l2norm + residual ----------------
__global__ __launch_bounds__(256) void k_entfin(const float* __restrict__ agg,
                                                float* __restrict__ cur,
                                                float* __restrict__ res){
  int wave=threadIdx.x>>6, lane=threadIdx.x&63;
  int r = blockIdx.x*4+wave;
  if(r>=N_ENT) return;
  float v = agg[(size_t)r*CH+lane];
  float nrm = sqrtf(waveReduceSum(v*v));
  float outv = v / fmaxf(nrm, 1e-12f);
  cur[(size_t)r*CH+lane]=outv;
  res[(size_t)r*CH+lane]+=outv;
}

// ---------------- final adj scatter ----------------
__global__ void k_scatter_adj(const int* __restrict__ knn_idx,
                              const float* __restrict__ knn_val,
                              const float* __restrict__ rowsum,
                              float coef, float* __restrict__ adj){
  int i = blockIdx.x*blockDim.x+threadIdx.x;
  if(i>=N_ENT*TOPKC) return;
  int row = i/TOPKC;
  int col = knn_idx[i];
  float v = knn_val[i];
  float dv = coef * v / (sqrtf(rowsum[row]) * sqrtf(rowsum[col]));
  atomicAdd(&adj[(size_t)row*N_ENT+col], dv);
}

extern "C" void kernel_launch(void* const* d_in, const int* in_sizes, int n_in,
                              void* d_out, int out_size, void* d_ws, size_t ws_size,
                              hipStream_t stream){
  const float* user_emb   = (const float*)d_in[0];
  const float* entity_emb = (const float*)d_in[1];
  const int*   edge_index = (const int*)d_in[2];
  const int*   edge_type  = (const int*)d_in[3];
  const int*   inter_idx  = (const int*)d_in[4];
  const float* inter_vals = (const float*)d_in[5];
  const float* W          = (const float*)d_in[6];

  const int* head  = edge_index;
  const int* tail  = edge_index + N_EDGEC;
  const int* irows = inter_idx;
  const int* icols = inter_idx + NNZC;

  float* out     = (float*)d_out;
  float* ent_res = out;
  float* usr_res = out + (size_t)N_ENT*CH;
  float* adj     = out + (size_t)N_ENT*CH + (size_t)N_USR*CH;

  char* wp = (char*)d_ws;
  auto alloc = [&](size_t bytes)->void*{
    void* p = (void*)wp; wp += (bytes+255)/256*256; return p;
  };
  float* cn      = (float*)alloc((size_t)N_ENT*CH*4);
  float* cur_ent = (float*)alloc((size_t)N_ENT*CH*4);
  float* cur_usr = (float*)alloc((size_t)N_USR*CH*4);
  float* agg     = (float*)alloc((size_t)N_ENT*CH*4);
  float* q       = (float*)alloc((size_t)N_ENT*NRELM1*4);
  int*   histE   = (int*)alloc((size_t)N_ENT*4);
  int*   startE  = (int*)alloc((size_t)(N_ENT+1)*4);
  int*   cursorE = (int*)alloc((size_t)N_ENT*4);
  int*   trS     = (int*)alloc((size_t)N_EDGEC*4);
  int*   histU   = (int*)alloc((size_t)N_USR*4);
  int*   startU  = (int*)alloc((size_t)(N_USR+1)*4);
  int*   cursorU = (int*)alloc((size_t)N_USR*4);
  int*   icolsS  = (int*)alloc((size_t)NNZC*4);
  float* ivalsS  = (float*)alloc((size_t)NNZC*4);
  int*   knn_idx0= (int*)alloc((size_t)N_ENT*TOPKC*4);
  float* knn_val0= (float*)alloc((size_t)N_ENT*TOPKC*4);
  float* rowsum0 = (float*)alloc((size_t)N_ENT*4);
  int*   knn_idx1= (int*)alloc((size_t)N_ENT*TOPKC*4);
  float* knn_val1= (float*)alloc((size_t)N_ENT*TOPKC*4);
  float* rowsum1 = (float*)alloc((size_t)N_ENT*4);

  // wbuf for edge softmax lives in the adj output region (256MB, idle during hops)
  float* wbuf = adj;

  // init
  hipMemsetAsync(histE, 0, (size_t)N_ENT*4, stream);
  hipMemsetAsync(histU, 0, (size_t)N_USR*4, stream);
  hipMemcpyAsync(ent_res, entity_emb, (size_t)N_ENT*CH*4, hipMemcpyDeviceToDevice, stream);
  hipMemcpyAsync(usr_res, user_emb,   (size_t)N_USR*CH*4, hipMemcpyDeviceToDevice, stream);
  hipMemcpyAsync(cur_ent, entity_emb, (size_t)N_ENT*CH*4, hipMemcpyDeviceToDevice, stream);
  hipMemcpyAsync(cur_usr, user_emb,   (size_t)N_USR*CH*4, hipMemcpyDeviceToDevice, stream);

  // counting sorts with fused payload gather (edges by head, inter by row)
  k_hist<<<1024,256,0,stream>>>(head, N_EDGEC, histE);
  k_hist<<<512,256,0,stream>>>(irows, NNZC, histU);
  k_scan<<<1,1024,0,stream>>>(histE, startE, cursorE, N_ENT);
  k_scan<<<1,1024,0,stream>>>(histU, startU, cursorU, N_USR);
  k_scatter_sortE<<<1024,256,0,stream>>>(head, tail, edge_type, N_EDGEC, cursorE, trS);
  k_scatter_sortU<<<512,256,0,stream>>>(irows, icols, inter_vals, NNZC, cursorU, icolsS, ivalsS);

  dim3 gg(N_ENT/128, N_ENT/128);

  // build_adj #1 on original entity_emb (sim matrix staged in the adj output region)
  k_rownorm<<<N_ENT/4,256,0,stream>>>(entity_emb, cn, N_ENT, 0.f);
  k_gemm_nt<<<gg,256,0,stream>>>(cn, adj);
  k_topk<<<N_ENT,64,0,stream>>>(adj, knn_idx0, knn_val0, rowsum0);

  // 2 hops
  for(int hop=0; hop<2; ++hop){
    k_q<<<N_ENT/4,256,0,stream>>>(cur_ent, W, q);
    k_edge_agg<<<N_ENT/4,256,0,stream>>>(trS, startE, cur_ent, W, q, wbuf, agg);
    k_user<<<N_USR/4,256,0,stream>>>(icolsS, ivalsS, startU, cur_ent, W, cur_usr, usr_res);
    k_entfin<<<N_ENT/4,256,0,stream>>>(agg, cur_ent, ent_res);
  }

  // build_adj #2 on entity_res_emb
  k_rownorm<<<N_ENT/4,256,0,stream>>>(ent_res, cn, N_ENT, 0.f);
  k_gemm_nt<<<gg,256,0,stream>>>(cn, adj);
  k_topk<<<N_ENT,64,0,stream>>>(adj, knn_idx1, knn_val1, rowsum1);

  // item_adj = 0.5*new + 0.5*origin, materialized dense
  hipMemsetAsync(adj, 0, (size_t)N_ENT*N_ENT*4, stream);
  int nsc = (N_ENT*TOPKC+255)/256;
  k_scatter_adj<<<nsc,256,0,stream>>>(knn_idx1, knn_val1, rowsum1, 0.5f, adj);
  k_scatter_adj<<<nsc,256,0,stream>>>(knn_idx0, knn_val0, rowsum0, 0.5f, adj);
}